// Round 12
// baseline (423.261 us; speedup 1.0000x reference)
//
#include <hip/hip_runtime.h>
#include <hip/hip_cooperative_groups.h>
#include <math.h>
#include <limits.h>

// Match numpy op-for-op: no fma contraction anywhere.
#pragma clang fp contract(off)

#define TPB 256
#define NWAVE 4          // waves per block (TPB/64)
#define KTOP 10
#define ISPLIT 64        // iou-scan splits per gt
#define GSPLIT 8         // gate-scan splits per gt
#define GCAP 4096        // max gated anchors per gt
#define CHUNKCAP 4480    // LDS gate buffer (>= ceil(N/GSPLIT)+TPB for N=33600)
#define MAXMULTI 4096

namespace cg = cooperative_groups;

typedef unsigned int u32;
typedef unsigned long long u64;
typedef unsigned char u8;

// pairwise IoU, identical op order to the numpy reference
__device__ __forceinline__ float f_iou(float ax0, float ay0, float ax1, float ay1,
                                       float bx0, float by0, float bx1, float by1) {
  float tlx = fmaxf(ax0, bx0);
  float tly = fmaxf(ay0, by0);
  float brx = fminf(ax1, bx1);
  float bry = fminf(ay1, by1);
  float w = fmaxf(brx - tlx, 0.0f);
  float h = fmaxf(bry - tly, 0.0f);
  float inter = w * h;
  float aa = fmaxf(ax1 - ax0, 0.0f) * fmaxf(ay1 - ay0, 0.0f);
  float ab = fmaxf(bx1 - bx0, 0.0f) * fmaxf(by1 - by0, 0.0f);
  float uni = aa + ab - inter;
  return inter / fmaxf(uni, 1e-7f);
}

// dv = -(L - L1), exact expression tree of the reference cls numerator
__device__ __forceinline__ float f_dv(float p) {
  float L  = fmaxf(logf(p), -100.0f);
  float L1 = fmaxf(log1pf(-p), -100.0f);
  return -(L - L1);
}

// full cost(n,g); identical op order to reference (cls = dv - sumL1).
__device__ __forceinline__ float f_cost(float iou_masked, float dv, float sumL1v,
                                        float px, float py, float sx, float sy,
                                        float bx0, float by0, float bx1, float by1,
                                        int vld) {
  if (!vld) return 100000000.0f;  // BIG
  float cls = dv - sumL1v;
  float l_ = px - bx0, t_ = py - by0, r_ = bx1 - px, b_ = by1 - py;
  bool ing = fminf(fminf(l_, t_), fminf(r_, b_)) > 0.0f;
  float gcx = (bx0 + bx1) * 0.5f;
  float gcy = (by0 + by1) * 0.5f;
  float cl = px - (gcx - 2.5f * sx);
  float ct = py - (gcy - 2.5f * sy);
  float cr = (gcx + 2.5f * sx) - px;
  float cb = (gcy + 2.5f * sy) - py;
  bool inc = fminf(fminf(cl, ct), fminf(cr, cb)) > 0.0f;
  float icost = -logf(iou_masked + 1e-7f);
  return (cls * 1.0f + icost * 3.0f) + ((ing && inc) ? 0.0f : 100000.0f);
}

// Sentinel fallback: val=-70000 (ws too small) / -80000 (coop launch failed)
__global__ __launch_bounds__(TPB) void k_fb(float* out, int Nout, float val) {
  int n = blockIdx.x * blockDim.x + threadIdx.x;
  if (n >= Nout) return;
  out[n] = 0.0f;
  out[Nout + n] = -1.0f;
  out[2 * Nout + n] = val;
}

// The whole SimOTA pipeline in ONE cooperative kernel, phases split by
// grid.sync(). Work units are grid-strided; roles chosen by unit index.
__global__ __launch_bounds__(TPB) void k_all(
    const float* pred, const float* priors, const float* dec,
    const float* gtb, const int* gtl,
    float* sumL1, u32* packed, u8* validArr,
    int* gateCnt, int* gateList, int* flags,
    float* iouV, int* mlist, int* mcnt,
    float* out, int N, int G, int C, int Nout)
{
  cg::grid_group grid = cg::this_grid();
  __shared__ int lbuf[CHUNKCAP];
  __shared__ int lcnt;
  __shared__ int gbase;
  const int tid = threadIdx.x;
  const int lane = tid & 63;
  const int wid = tid >> 6;
  const int nblk = gridDim.x;
  const float4* dec4 = reinterpret_cast<const float4*>(dec);
  const float4* pri4 = reinterpret_cast<const float4*>(priors);

  // ---------- Phase A: zero all state (ws is poisoned every launch) ----------
  for (int i = blockIdx.x * TPB + tid; i < N; i += nblk * TPB) {
    packed[i] = 0;
    validArr[i] = 0;
  }
  for (int i = blockIdx.x * TPB + tid; i < G; i += nblk * TPB) {
    gateCnt[i] = 0;
    flags[i] = 0;
  }
  if (blockIdx.x == 0 && tid == 0) *mcnt = 0;
  grid.sync();

  // ---------- Phase B: per-anchor sumL1  +  per-(g,chunk) gating ----------
  int sumUnits = (N * 8 + TPB - 1) / TPB;
  int gateUnits = G * GSPLIT;
  int chunkG = (N + GSPLIT - 1) / GSPLIT;
  for (int u = blockIdx.x; u < sumUnits + gateUnits; u += nblk) {
    if (u < sumUnits) {
      // sum role: 8 lanes per anchor; lane j owns classes i ≡ j (mod 8)
      // ascending == numpy 8-accumulator pairwise order; shfl tree == combine.
      int t = u * TPB + tid;
      int n = t >> 3, j = t & 7;
      if (n < N) {
        const float* pr = pred + (size_t)n * C;
        int lim = C - (C % 8);
        float r = 0.0f;
        for (int i = j; i < lim; i += 8) r += fmaxf(log1pf(-pr[i]), -100.0f);
        r += __shfl_down(r, 1, 8);
        r += __shfl_down(r, 2, 8);
        r += __shfl_down(r, 4, 8);
        if (j == 0) {
          for (int i = lim; i < C; ++i) r += fmaxf(log1pf(-pr[i]), -100.0f);
          sumL1[n] = r;
        }
      }
    } else {
      // gate role: LDS-buffered compaction, ONE global atomic per flush.
      int bidg = u - sumUnits;
      int g = bidg / GSPLIT, s = bidg % GSPLIT;
      int start = s * chunkG;
      int end = start + chunkG; if (end > N) end = N;
      float x0 = gtb[g * 4 + 0], y0 = gtb[g * 4 + 1];
      float x1 = gtb[g * 4 + 2], y1 = gtb[g * 4 + 3];
      float gcx = (x0 + x1) * 0.5f, gcy = (y0 + y1) * 0.5f;
      int* gl = gateList + (size_t)g * GCAP;
      if (tid == 0) lcnt = 0;
      __syncthreads();
      for (int nb = start; nb < end; nb += TPB) {
        __syncthreads();  // make lcnt uniform-visible
        if (lcnt + TPB > CHUNKCAP) {
          int total = lcnt;
          if (tid == 0) gbase = atomicAdd(&gateCnt[g], total);
          __syncthreads();
          int base = gbase;
          for (int i = tid; i < total; i += TPB) {
            int slot = base + i;
            if (slot < GCAP) gl[slot] = lbuf[i];
            else flags[g] = 1;  // overflow -> exact full scan for this g
          }
          __syncthreads();
          if (tid == 0) lcnt = 0;
          __syncthreads();
        }
        int n = nb + tid;
        bool gated = false;
        if (n < end) {
          float4 pv = pri4[n];
          float px = pv.x, py = pv.y, sx = pv.z, sy = pv.w;
          float l_ = px - x0, t_ = py - y0, r_ = x1 - px, b_ = y1 - py;
          bool ing = fminf(fminf(l_, t_), fminf(r_, b_)) > 0.0f;
          float cl = px - (gcx - 2.5f * sx), ct = py - (gcy - 2.5f * sy);
          float cr = (gcx + 2.5f * sx) - px, cb = (gcy + 2.5f * sy) - py;
          bool inc = fminf(fminf(cl, ct), fminf(cr, cb)) > 0.0f;
          if (ing || inc) validArr[n] = 1;  // benign same-value race across g
          gated = ing && inc;
        }
        u64 mask = __ballot(gated);
        int wcnt = __popcll(mask);
        int wbase = 0;
        if (lane == 0 && wcnt > 0) wbase = atomicAdd(&lcnt, wcnt);  // LDS atomic
        wbase = __shfl(wbase, 0);
        if (gated) {
          int p = __popcll(mask & ((1ull << lane) - 1ull));
          lbuf[wbase + p] = n;
        }
      }
      __syncthreads();
      int total = lcnt;
      if (tid == 0 && total > 0) gbase = atomicAdd(&gateCnt[g], total);
      __syncthreads();
      if (total > 0) {
        int base = gbase;
        for (int i = tid; i < total; i += TPB) {
          int slot = base + i;
          if (slot < GCAP) gl[slot] = lbuf[i];
          else flags[g] = 1;
        }
      }
      __syncthreads();
    }
  }
  grid.sync();

  // ---------- Phase C: per-(g,split) top-10 IoU (one wave per unit) ----------
  int chunkI = (N + ISPLIT - 1) / ISPLIT;
  for (int u = blockIdx.x * NWAVE + wid; u < G * ISPLIT; u += nblk * NWAVE) {
    int g = u / ISPLIT, s = u % ISPLIT;
    int start = s * chunkI;
    int end = start + chunkI; if (end > N) end = N;
    float bx0 = gtb[g * 4 + 0], by0 = gtb[g * 4 + 1];
    float bx1 = gtb[g * 4 + 2], by1 = gtb[g * 4 + 3];
    float iv[KTOP];
#pragma unroll
    for (int j = 0; j < KTOP; ++j) iv[j] = 0.0f;  // iou>=0; zero-pad sum-invariant
    for (int n = start + lane; n < end; n += 64) {
      float4 dvb = dec4[n];
      float iou = f_iou(dvb.x, dvb.y, dvb.z, dvb.w, bx0, by0, bx1, by1);
      if (!validArr[n]) iou = 0.0f;
      if (iou > iv[KTOP - 1]) {
        float cu = iou;
#pragma unroll
        for (int j = 0; j < KTOP; ++j) {
          if (cu > iv[j]) { float tv = iv[j]; iv[j] = cu; cu = tv; }
        }
      }
    }
    // wave tournament: 10 rounds of max + owner pop (values only)
#pragma unroll
    for (int r = 0; r < KTOP; ++r) {
      float v = iv[0]; int owner = lane;
#pragma unroll
      for (int off = 32; off > 0; off >>= 1) {
        float v2 = __shfl_down(v, off);
        int o2 = __shfl_down(owner, off);
        if (v2 > v || (v2 == v && o2 < owner)) { v = v2; owner = o2; }
      }
      float wv = __shfl(v, 0);
      int wo = __shfl(owner, 0);
      if (lane == 0) iouV[u * KTOP + r] = wv;
      if (lane == wo) {
#pragma unroll
        for (int j = 0; j < KTOP - 1; ++j) iv[j] = iv[j + 1];
        iv[KTOP - 1] = 0.0f;
      }
    }
  }
  grid.sync();

  // ---------- Phase D: per-g dynamic_k + cost top-k + scatter (one wave) ----------
  for (int g = blockIdx.x * NWAVE + wid; g < G; g += nblk * NWAVE) {
    int base = g * ISPLIT * KTOP;
    const int TOT = ISPLIT * KTOP;        // 640
    const int PER = TOT / 64;             // 10
    float il[PER];
#pragma unroll
    for (int k = 0; k < PER; ++k) il[k] = 0.0f;
#pragma unroll
    for (int k = 0; k < PER; ++k) {
      float v = iouV[base + lane + k * 64];
      if (v > il[PER - 1]) {
#pragma unroll
        for (int j = 0; j < PER; ++j) {
          if (v > il[j]) { float tv = il[j]; il[j] = v; v = tv; }
        }
      }
    }
    float rv[KTOP];
#pragma unroll
    for (int r = 0; r < KTOP; ++r) {
      float v = il[0]; int owner = lane;
#pragma unroll
      for (int off = 32; off > 0; off >>= 1) {
        float v2 = __shfl_down(v, off);
        int o2 = __shfl_down(owner, off);
        if (v2 > v || (v2 == v && o2 < owner)) { v = v2; owner = o2; }
      }
      float wv = __shfl(v, 0);
      int wo = __shfl(owner, 0);
      rv[r] = wv;
      if (lane == wo) {
#pragma unroll
        for (int j = 0; j < PER - 1; ++j) il[j] = il[j + 1];
        il[PER - 1] = 0.0f;
      }
    }
    // numpy pairwise order for a 10-element sum (all lanes identical)
    float s8 = ((rv[0] + rv[1]) + (rv[2] + rv[3])) + ((rv[4] + rv[5]) + (rv[6] + rv[7]));
    s8 += rv[8];
    s8 += rv[9];
    int dk = (int)s8;  // trunc toward zero == astype(int32)
    if (dk < 1) dk = 1;
    if (dk > KTOP) dk = KTOP;

    float bx0 = gtb[g * 4 + 0], by0 = gtb[g * 4 + 1];
    float bx1 = gtb[g * 4 + 2], by1 = gtb[g * 4 + 3];
    int lab = gtl[g];
    if (lab < 0) lab = 0;
    if (lab >= C) lab = C - 1;

    float cv[KTOP]; int ci[KTOP];
#pragma unroll
    for (int j = 0; j < KTOP; ++j) { cv[j] = 1e30f; ci[j] = INT_MAX; }

    int cnt = gateCnt[g];
    if (!flags[g] && cnt >= KTOP) {
      // fast path: gated-only (gated cost strictly below ungated/invalid)
      const int* gl = gateList + (size_t)g * GCAP;
      for (int i = lane; i < cnt; i += 64) {
        int n = gl[i];
        float4 dvb = dec4[n];
        float iou = f_iou(dvb.x, dvb.y, dvb.z, dvb.w, bx0, by0, bx1, by1);
        float dv = f_dv(pred[(size_t)n * C + lab]);
        float cls = dv - sumL1[n];
        float icost = -logf(iou + 1e-7f);
        float c = (cls * 1.0f + icost * 3.0f) + 0.0f;  // gate true -> +0 exactly
        bool ins = (c < cv[KTOP - 1]) || (c == cv[KTOP - 1] && n < ci[KTOP - 1]);
        if (ins) {
          float cu = c; int cui = n;
#pragma unroll
          for (int j = 0; j < KTOP; ++j) {
            bool lt = (cu < cv[j]) || (cu == cv[j] && cui < ci[j]);
            if (lt) { float tv = cv[j]; int ti = ci[j]; cv[j] = cu; ci[j] = cui; cu = tv; cui = ti; }
          }
        }
      }
    } else {
      // exact full scan (rare: gateCnt<10 or overflow)
      for (int n = lane; n < N; n += 64) {
        float4 dvb = dec4[n];
        int vld = validArr[n];
        float iou = f_iou(dvb.x, dvb.y, dvb.z, dvb.w, bx0, by0, bx1, by1);
        if (!vld) iou = 0.0f;
        float dv = f_dv(pred[(size_t)n * C + lab]);
        float4 pv = pri4[n];
        float c = f_cost(iou, dv, sumL1[n], pv.x, pv.y, pv.z, pv.w,
                         bx0, by0, bx1, by1, vld);
        bool ins = (c < cv[KTOP - 1]) || (c == cv[KTOP - 1] && n < ci[KTOP - 1]);
        if (ins) {
          float cu = c; int cui = n;
#pragma unroll
          for (int j = 0; j < KTOP; ++j) {
            bool lt = (cu < cv[j]) || (cu == cv[j] && cui < ci[j]);
            if (lt) { float tv = cv[j]; int ti = ci[j]; cv[j] = cu; ci[j] = cui; cu = tv; cui = ti; }
          }
        }
      }
    }

    // dk rounds of lexicographic min + scatter
    for (int r = 0; r < KTOP; ++r) {
      float v = cv[0]; int idx = ci[0];
#pragma unroll
      for (int off = 32; off > 0; off >>= 1) {
        float v2 = __shfl_down(v, off);
        int i2 = __shfl_down(idx, off);
        if (v2 < v || (v2 == v && i2 < idx)) { v = v2; idx = i2; }
      }
      int wi = __shfl(idx, 0);
      if (r < dk && lane == 0 && wi >= 0 && wi < N) {
        // count in high 16 bits; sum of g in low 16 (exact g when count==1)
        atomicAdd(&packed[wi], (1u << 16) | (u32)g);
      }
      if (ci[0] == wi) {  // candidate n unique per g -> exactly one lane pops
#pragma unroll
        for (int j = 0; j < KTOP - 1; ++j) { cv[j] = cv[j + 1]; ci[j] = ci[j + 1]; }
        cv[KTOP - 1] = 1e30f; ci[KTOP - 1] = INT_MAX;
      }
      if (r + 1 >= dk) break;
    }
  }
  grid.sync();

  // ---------- Phase E: resolve cnt 0/1, queue multi ----------
  for (int n = blockIdx.x * TPB + tid; n < N; n += nblk * TPB) {
    if (n >= Nout) break;
    u32 pk = packed[n];
    int cnt = (int)(pk >> 16);
    float o0 = 0.0f, o1 = -1.0f, o2 = -100000.0f;
    if (cnt > 1) {
      int idx = atomicAdd(mcnt, 1);
      if (idx < MAXMULTI) mlist[idx] = n;
      // defaults written now; phase F overwrites after grid.sync
    }
    if (cnt == 1) {
      int g = (int)(pk & 0xFFFFu);
      if (g < 0) g = 0;
      if (g >= G) g = G - 1;
      float4 dv = dec4[n];
      float x0 = gtb[g * 4 + 0], y0 = gtb[g * 4 + 1];
      float x1 = gtb[g * 4 + 2], y1 = gtb[g * 4 + 3];
      float iou = f_iou(dv.x, dv.y, dv.z, dv.w, x0, y0, x1, y1);
      if (!validArr[n]) iou = 0.0f;
      o0 = (float)g; o1 = 1.0f; o2 = iou;
    }
    out[n]            = o0;
    out[Nout + n]     = o1;
    out[2 * Nout + n] = o2;
  }
  grid.sync();

  // ---------- Phase F: multi-match argmin, one wave per anchor ----------
  int total = *mcnt;
  if (total > MAXMULTI) total = MAXMULTI;
  for (int w = blockIdx.x * NWAVE + wid; w < total; w += nblk * NWAVE) {
    int n = mlist[w];
    float4 dvb = dec4[n];
    float4 pv = pri4[n];
    float s1 = sumL1[n];
    int vld = validArr[n];
    float best = 1e30f; int bg = INT_MAX;
    for (int gg = lane; gg < G; gg += 64) {
      float x0 = gtb[gg * 4 + 0], y0 = gtb[gg * 4 + 1];
      float x1 = gtb[gg * 4 + 2], y1 = gtb[gg * 4 + 3];
      float iou = f_iou(dvb.x, dvb.y, dvb.z, dvb.w, x0, y0, x1, y1);
      if (!vld) iou = 0.0f;
      int lb = gtl[gg];
      if (lb < 0) lb = 0;
      if (lb >= C) lb = C - 1;
      float dv = f_dv(pred[(size_t)n * C + lb]);
      float c = f_cost(iou, dv, s1, pv.x, pv.y, pv.z, pv.w, x0, y0, x1, y1, vld);
      if (c < best || (c == best && gg < bg)) { best = c; bg = gg; }
    }
#pragma unroll
    for (int off = 32; off > 0; off >>= 1) {
      float v2 = __shfl_down(best, off);
      int g2 = __shfl_down(bg, off);
      if (v2 < best || (v2 == best && g2 < bg)) { best = v2; bg = g2; }
    }
    if (lane == 0 && n < Nout) {
      int g = bg;
      if (g < 0 || g >= G) g = 0;
      float x0 = gtb[g * 4 + 0], y0 = gtb[g * 4 + 1];
      float x1 = gtb[g * 4 + 2], y1 = gtb[g * 4 + 3];
      float iou = f_iou(dvb.x, dvb.y, dvb.z, dvb.w, x0, y0, x1, y1);
      if (!vld) iou = 0.0f;
      out[n]            = (float)g;
      out[Nout + n]     = 1.0f;
      out[2 * Nout + n] = iou;
    }
  }
}

extern "C" void kernel_launch(void* const* d_in, const int* in_sizes, int n_in,
                              void* d_out, int out_size, void* d_ws, size_t ws_size,
                              hipStream_t stream) {
  const float* pred   = (const float*)d_in[0];  // (N,C) f32
  const float* priors = (const float*)d_in[1];  // (N,4) f32
  const float* dec    = (const float*)d_in[2];  // (N,4) f32
  const float* gtb    = (const float*)d_in[3];  // (G,4) f32
  const int*   gtl    = (const int*)d_in[4];    // (G,)  int32
  int N = in_sizes[2] / 4;
  int G = in_sizes[3] / 4;
  int C = in_sizes[0] / N;
  int Nout = out_size / 3;
  float* out = (float*)d_out;

  // ws layout (16B-aligned blocks)
  size_t offPacked = 0;
  size_t offSum    = offPacked + (size_t)N * 4;
  size_t offValid  = offSum + (size_t)N * 4;
  size_t offGate   = (offValid + (size_t)N + 15) & ~(size_t)15;
  size_t offFlags  = offGate + (size_t)G * 4;
  size_t offMcnt   = offFlags + (size_t)G * 4;
  size_t offMlist  = (offMcnt + 4 + 15) & ~(size_t)15;
  size_t offGlist  = (offMlist + (size_t)MAXMULTI * 4 + 15) & ~(size_t)15;
  size_t offIouV   = offGlist + (size_t)G * GCAP * 4;
  size_t need      = offIouV + (size_t)G * ISPLIT * KTOP * 4;

  dim3 b(TPB);
  int oblk = (Nout + TPB - 1) / TPB;
  if (ws_size < need || d_ws == nullptr) {
    k_fb<<<oblk, b, 0, stream>>>(out, Nout, -70000.0f);
    return;
  }
  char* wsb = (char*)d_ws;
  u32* packed   = (u32*)(wsb + offPacked);
  float* sumL1  = (float*)(wsb + offSum);
  u8* validArr  = (u8*)(wsb + offValid);
  int* gateCnt  = (int*)(wsb + offGate);
  int* flags    = (int*)(wsb + offFlags);
  int* mcnt     = (int*)(wsb + offMcnt);
  int* mlist    = (int*)(wsb + offMlist);
  int* gateList = (int*)(wsb + offGlist);
  float* iouV   = (float*)(wsb + offIouV);

  // co-residency-safe grid for cooperative launch
  int maxBlocksPerCU = 0;
  hipError_t oe = hipOccupancyMaxActiveBlocksPerMultiprocessor(
      &maxBlocksPerCU, (const void*)k_all, TPB, 0);
  if (oe != hipSuccess || maxBlocksPerCU < 1) maxBlocksPerCU = 1;
  int grid = maxBlocksPerCU * 256;          // 256 CUs on MI355X
  if (grid > 1024) grid = 1024;
  if (grid < 64) grid = 64;

  void* args[] = {
    (void*)&pred, (void*)&priors, (void*)&dec, (void*)&gtb, (void*)&gtl,
    (void*)&sumL1, (void*)&packed, (void*)&validArr,
    (void*)&gateCnt, (void*)&gateList, (void*)&flags,
    (void*)&iouV, (void*)&mlist, (void*)&mcnt,
    (void*)&out, (void*)&N, (void*)&G, (void*)&C, (void*)&Nout
  };
  hipError_t err = hipLaunchCooperativeKernel(
      (const void*)k_all, dim3(grid), dim3(TPB), args, 0, stream);
  if (err != hipSuccess) {
    // diagnosable sentinel: -80000 at out2 == cooperative launch rejected
    k_fb<<<oblk, b, 0, stream>>>(out, Nout, -80000.0f);
  }
}

// Round 13
// 174.700 us; speedup vs baseline: 2.4228x; 2.4228x over previous
//
#include <hip/hip_runtime.h>
#include <math.h>
#include <limits.h>

// Match numpy op-for-op: no fma contraction anywhere.
#pragma clang fp contract(off)

#define TPB 256
#define KTOP 10
#define GSPLIT 8
#define GSLICE 4352   // per-(g,chunk) list capacity; >= ceil(N/GSPLIT) guarded on host
#define MAXG 512

typedef unsigned int u32;
typedef unsigned long long u64;
typedef unsigned char u8;

// pairwise IoU, identical op order to the numpy reference
__device__ __forceinline__ float f_iou(float ax0, float ay0, float ax1, float ay1,
                                       float bx0, float by0, float bx1, float by1) {
  float tlx = fmaxf(ax0, bx0);
  float tly = fmaxf(ay0, by0);
  float brx = fminf(ax1, bx1);
  float bry = fminf(ay1, by1);
  float w = fmaxf(brx - tlx, 0.0f);
  float h = fmaxf(bry - tly, 0.0f);
  float inter = w * h;
  float aa = fmaxf(ax1 - ax0, 0.0f) * fmaxf(ay1 - ay0, 0.0f);
  float ab = fmaxf(bx1 - bx0, 0.0f) * fmaxf(by1 - by0, 0.0f);
  float uni = aa + ab - inter;
  return inter / fmaxf(uni, 1e-7f);
}

// dv = -(L - L1), exact expression tree of the reference cls numerator
__device__ __forceinline__ float f_dv(float p) {
  float L  = fmaxf(logf(p), -100.0f);
  float L1 = fmaxf(log1pf(-p), -100.0f);
  return -(L - L1);
}

// full cost(n,g); identical op order to reference (cls = dv - sumL1).
__device__ __forceinline__ float f_cost(float iou_masked, float dv, float sumL1v,
                                        float px, float py, float sx, float sy,
                                        float bx0, float by0, float bx1, float by1,
                                        int vld) {
  if (!vld) return 100000000.0f;  // BIG
  float cls = dv - sumL1v;
  float l_ = px - bx0, t_ = py - by0, r_ = bx1 - px, b_ = by1 - py;
  bool ing = fminf(fminf(l_, t_), fminf(r_, b_)) > 0.0f;
  float gcx = (bx0 + bx1) * 0.5f;
  float gcy = (by0 + by1) * 0.5f;
  float cl = px - (gcx - 2.5f * sx);
  float ct = py - (gcy - 2.5f * sy);
  float cr = (gcx + 2.5f * sx) - px;
  float cb = (gcy + 2.5f * sy) - py;
  bool inc = fminf(fminf(cl, ct), fminf(cr, cb)) > 0.0f;
  float icost = -logf(iou_masked + 1e-7f);
  return (cls * 1.0f + icost * 3.0f) + ((ing && inc) ? 0.0f : 100000.0f);
}

// Sentinel fallback: -70000 (ws too small) / -60000 (shape exceeds static caps)
__global__ __launch_bounds__(TPB) void k_fb(float* out, int Nout, float val) {
  int n = blockIdx.x * blockDim.x + threadIdx.x;
  if (n >= Nout) return;
  out[n] = 0.0f;
  out[Nout + n] = -1.0f;
  out[2 * Nout + n] = val;
}

// Phase 1: blocks [0, sumBlocks) — per-anchor sumL1 + valid flag + packed=0
// (all written unconditionally; no init assumptions). Blocks [sumBlocks, ...)
// — gating for one (g, chunk): LDS-compacted gated list written to a PRIVATE
// per-(g,chunk) slice + count. No global atomics anywhere.
__global__ __launch_bounds__(TPB) void k_phase1(
    const float* pred, const float* priors, const float* gtb,
    float* sumL1, u32* packed, u8* validArr,
    int* gateCnt2, int* gateList,
    int N, int G, int C, int sumBlocks)
{
  __shared__ float sg[MAXG * 4];
  __shared__ int lbuf[GSLICE];
  __shared__ int lcnt;
  const int tid = threadIdx.x;
  const int lane = tid & 63;
  const float4* pri4 = reinterpret_cast<const float4*>(priors);

  if ((int)blockIdx.x < sumBlocks) {
    // ---- sum role: 8 lanes per anchor ----
    for (int i = tid; i < G * 4; i += TPB) sg[i] = gtb[i];
    __syncthreads();
    int t = blockIdx.x * TPB + tid;
    int n = t >> 3, j = t & 7;
    if (n >= N) return;  // whole 8-lane groups exit together
    float4 pv = pri4[n];
    float px = pv.x, py = pv.y, sx = pv.z, sy = pv.w;
    // valid = OR over g of (in_box || in_center); lane j owns g ≡ j (mod 8)
    int valid = 0;
    for (int g = j; g < G; g += 8) {
      float x0 = sg[g * 4 + 0], y0 = sg[g * 4 + 1], x1 = sg[g * 4 + 2], y1 = sg[g * 4 + 3];
      float l_ = px - x0, t_ = py - y0, r_ = x1 - px, b_ = y1 - py;
      bool ing = fminf(fminf(l_, t_), fminf(r_, b_)) > 0.0f;
      float gcx = (x0 + x1) * 0.5f, gcy = (y0 + y1) * 0.5f;
      float cl = px - (gcx - 2.5f * sx), ct = py - (gcy - 2.5f * sy);
      float cr = (gcx + 2.5f * sx) - px, cb = (gcy + 2.5f * sy) - py;
      bool inc = fminf(fminf(cl, ct), fminf(cr, cb)) > 0.0f;
      valid |= (ing || inc) ? 1 : 0;
    }
    valid |= __shfl_xor(valid, 1, 8);
    valid |= __shfl_xor(valid, 2, 8);
    valid |= __shfl_xor(valid, 4, 8);
    // sumL1: lane j owns classes i ≡ j (mod 8) ascending == numpy 8-acc
    // pairwise order; shfl tree == ((r0+r1)+(r2+r3))+((r4+r5)+(r6+r7)).
    const float* pr = pred + (size_t)n * C;
    int lim = C - (C % 8);
    float r = 0.0f;
    for (int i = j; i < lim; i += 8) r += fmaxf(log1pf(-pr[i]), -100.0f);
    r += __shfl_down(r, 1, 8);
    r += __shfl_down(r, 2, 8);
    r += __shfl_down(r, 4, 8);
    if (j == 0) {
      for (int i = lim; i < C; ++i) r += fmaxf(log1pf(-pr[i]), -100.0f);
      sumL1[n] = r;
      validArr[n] = (u8)valid;  // unconditional: every n written exactly once
      packed[n] = 0;            // ws re-poisoned every launch — must re-zero
    }
    return;
  }

  // ---- gate role ----
  int bidg = blockIdx.x - sumBlocks;
  int g = bidg / GSPLIT, s = bidg % GSPLIT;
  int chunk = (N + GSPLIT - 1) / GSPLIT;  // host guarantees chunk <= GSLICE
  int start = s * chunk;
  int end = start + chunk; if (end > N) end = N;
  float x0 = gtb[g * 4 + 0], y0 = gtb[g * 4 + 1];
  float x1 = gtb[g * 4 + 2], y1 = gtb[g * 4 + 3];
  float gcx = (x0 + x1) * 0.5f, gcy = (y0 + y1) * 0.5f;
  if (tid == 0) lcnt = 0;
  __syncthreads();
  for (int nb = start; nb < end; nb += TPB) {
    int n = nb + tid;
    bool gated = false;
    if (n < end) {
      float4 pv = pri4[n];
      float px = pv.x, py = pv.y, sx = pv.z, sy = pv.w;
      float l_ = px - x0, t_ = py - y0, r_ = x1 - px, b_ = y1 - py;
      bool ing = fminf(fminf(l_, t_), fminf(r_, b_)) > 0.0f;
      float cl = px - (gcx - 2.5f * sx), ct = py - (gcy - 2.5f * sy);
      float cr = (gcx + 2.5f * sx) - px, cb = (gcy + 2.5f * sy) - py;
      bool inc = fminf(fminf(cl, ct), fminf(cr, cb)) > 0.0f;
      gated = ing && inc;
    }
    u64 mask = __ballot(gated);
    int wcnt = __popcll(mask);
    int wbase = 0;
    if (lane == 0 && wcnt > 0) wbase = atomicAdd(&lcnt, wcnt);  // LDS atomic only
    wbase = __shfl(wbase, 0);
    if (gated) {
      int p = __popcll(mask & ((1ull << lane) - 1ull));
      lbuf[wbase + p] = n;  // lcnt <= chunk <= GSLICE: no overflow possible
    }
  }
  __syncthreads();
  int total = lcnt;
  if (tid == 0) gateCnt2[bidg] = total;  // written exactly once — no zero-init
  int* gl = gateList + (size_t)bidg * GSLICE;
  for (int i = tid; i < total; i += TPB) gl[i] = lbuf[i];
}

// Phase 2: ONE BLOCK per g. (a) iou top-10 over all N (per-thread lists →
// per-wave shfl tournaments → wave-0 40-value merge) → dynamic_k;
// (b) cost top-10 over the gated candidates (strictly below any
// ungated/invalid cost when total >= 10; else exact full scan), scatter.
__global__ __launch_bounds__(TPB) void k_phase2(
    const float* pred, const float* priors, const float* dec,
    const float* gtb, const int* gtl, const float* sumL1, const u8* validArr,
    const int* gateCnt2, const int* gateList,
    u32* packed, int N, int G, int C)
{
  int g = blockIdx.x;
  int tid = threadIdx.x, lane = tid & 63, wid = tid >> 6;
  __shared__ float wlv[4 * KTOP];
  __shared__ int   wli[4 * KTOP];
  __shared__ int sdk;
  float bx0 = gtb[g * 4 + 0], by0 = gtb[g * 4 + 1];
  float bx1 = gtb[g * 4 + 2], by1 = gtb[g * 4 + 3];
  const float4* dec4 = reinterpret_cast<const float4*>(dec);

  // ---- per-thread iou top-10 (zero-init: iou>=0, zero-pad sum-invariant) ----
  float iv[KTOP];
#pragma unroll
  for (int j = 0; j < KTOP; ++j) iv[j] = 0.0f;
  for (int n = tid; n < N; n += TPB) {
    float4 d = dec4[n];
    float iou = f_iou(d.x, d.y, d.z, d.w, bx0, by0, bx1, by1);
    if (!validArr[n]) iou = 0.0f;
    if (iou > iv[KTOP - 1]) {
      float cu = iou;
#pragma unroll
      for (int j = 0; j < KTOP; ++j) {
        if (cu > iv[j]) { float tv = iv[j]; iv[j] = cu; cu = tv; }
      }
    }
  }
  // per-wave tournament: 10 rounds of max + owner pop (values only)
#pragma unroll
  for (int r = 0; r < KTOP; ++r) {
    float v = iv[0]; int owner = lane;
#pragma unroll
    for (int off = 32; off > 0; off >>= 1) {
      float v2 = __shfl_down(v, off);
      int o2 = __shfl_down(owner, off);
      if (v2 > v || (v2 == v && o2 < owner)) { v = v2; owner = o2; }
    }
    float wv = __shfl(v, 0);
    int wo = __shfl(owner, 0);
    if (lane == 0) wlv[wid * KTOP + r] = wv;
    if (lane == wo) {
#pragma unroll
      for (int j = 0; j < KTOP - 1; ++j) iv[j] = iv[j + 1];
      iv[KTOP - 1] = 0.0f;
    }
  }
  __syncthreads();
  // wave 0: top-10 of the 40 wave-top values (union contains global top-10)
  if (wid == 0) {
    float v = (lane < 4 * KTOP) ? wlv[lane] : 0.0f;
    float rv[KTOP];
#pragma unroll
    for (int r = 0; r < KTOP; ++r) {
      float m = v; int owner = lane;
#pragma unroll
      for (int off = 32; off > 0; off >>= 1) {
        float v2 = __shfl_down(m, off);
        int o2 = __shfl_down(owner, off);
        if (v2 > m || (v2 == m && o2 < owner)) { m = v2; owner = o2; }
      }
      float wv = __shfl(m, 0);
      int wo = __shfl(owner, 0);
      rv[r] = wv;
      if (lane == wo) v = 0.0f;  // single-value consume
    }
    // numpy pairwise order for a 10-element sum
    float s8 = ((rv[0] + rv[1]) + (rv[2] + rv[3])) + ((rv[4] + rv[5]) + (rv[6] + rv[7]));
    s8 += rv[8];
    s8 += rv[9];
    int dk = (int)s8;  // trunc toward zero == astype(int32)
    if (dk < 1) dk = 1;
    if (dk > KTOP) dk = KTOP;
    if (lane == 0) sdk = dk;
  }
  __syncthreads();
  int dk = sdk;

  // ---- cost top-10 ----
  int lab = gtl[g];
  if (lab < 0) lab = 0;
  if (lab >= C) lab = C - 1;
  float cv[KTOP]; int ci[KTOP];
#pragma unroll
  for (int j = 0; j < KTOP; ++j) { cv[j] = 1e30f; ci[j] = INT_MAX; }

  int total = 0;
  for (int s = 0; s < GSPLIT; ++s) total += gateCnt2[g * GSPLIT + s];

  if (total >= KTOP) {
    // fast path: gated-only (gated cost strictly below ungated/invalid)
    for (int s = 0; s < GSPLIT; ++s) {
      int cs = gateCnt2[g * GSPLIT + s];
      const int* gl = gateList + (size_t)(g * GSPLIT + s) * GSLICE;
      for (int i = tid; i < cs; i += TPB) {
        int n = gl[i];
        float4 d = dec4[n];
        float iou = f_iou(d.x, d.y, d.z, d.w, bx0, by0, bx1, by1);
        float dv = f_dv(pred[(size_t)n * C + lab]);
        float cls = dv - sumL1[n];
        float icost = -logf(iou + 1e-7f);
        float c = (cls * 1.0f + icost * 3.0f) + 0.0f;  // gate true -> +0 exactly
        bool ins = (c < cv[KTOP - 1]) || (c == cv[KTOP - 1] && n < ci[KTOP - 1]);
        if (ins) {
          float cu = c; int cui = n;
#pragma unroll
          for (int j = 0; j < KTOP; ++j) {
            bool lt = (cu < cv[j]) || (cu == cv[j] && cui < ci[j]);
            if (lt) { float tv = cv[j]; int ti = ci[j]; cv[j] = cu; ci[j] = cui; cu = tv; cui = ti; }
          }
        }
      }
    }
  } else {
    // exact full scan (rare: fewer than 10 gated anchors for this g)
    const float4* pri4 = reinterpret_cast<const float4*>(priors);
    for (int n = tid; n < N; n += TPB) {
      float4 d = dec4[n];
      int vld = validArr[n];
      float iou = f_iou(d.x, d.y, d.z, d.w, bx0, by0, bx1, by1);
      if (!vld) iou = 0.0f;
      float dv = f_dv(pred[(size_t)n * C + lab]);
      float4 pv = pri4[n];
      float c = f_cost(iou, dv, sumL1[n], pv.x, pv.y, pv.z, pv.w,
                       bx0, by0, bx1, by1, vld);
      bool ins = (c < cv[KTOP - 1]) || (c == cv[KTOP - 1] && n < ci[KTOP - 1]);
      if (ins) {
        float cu = c; int cui = n;
#pragma unroll
        for (int j = 0; j < KTOP; ++j) {
          bool lt = (cu < cv[j]) || (cu == cv[j] && cui < ci[j]);
          if (lt) { float tv = cv[j]; int ti = ci[j]; cv[j] = cu; ci[j] = cui; cu = tv; cui = ti; }
        }
      }
    }
  }

  // per-wave tournament: lexicographic (value,index) min + list pop
#pragma unroll
  for (int r = 0; r < KTOP; ++r) {
    float v = cv[0]; int idx = ci[0];
#pragma unroll
    for (int off = 32; off > 0; off >>= 1) {
      float v2 = __shfl_down(v, off);
      int i2 = __shfl_down(idx, off);
      if (v2 < v || (v2 == v && i2 < idx)) { v = v2; idx = i2; }
    }
    float wv = __shfl(v, 0);
    int wi = __shfl(idx, 0);
    if (lane == 0) { wlv[wid * KTOP + r] = wv; wli[wid * KTOP + r] = wi; }
    if (ci[0] == wi && wi != INT_MAX) {  // n unique per g -> one lane pops
#pragma unroll
      for (int j = 0; j < KTOP - 1; ++j) { cv[j] = cv[j + 1]; ci[j] = ci[j + 1]; }
      cv[KTOP - 1] = 1e30f; ci[KTOP - 1] = INT_MAX;
    }
  }
  __syncthreads();
  // wave 0: global top-dk of the 40 pairs, scatter
  if (wid == 0) {
    float v; int idx;
    if (lane < 4 * KTOP) { v = wlv[lane]; idx = wli[lane]; }
    else { v = 1e30f; idx = INT_MAX; }
    for (int r = 0; r < dk; ++r) {
      float m = v; int mi = idx; int owner = lane;
#pragma unroll
      for (int off = 32; off > 0; off >>= 1) {
        float v2 = __shfl_down(m, off);
        int i2 = __shfl_down(mi, off);
        int o2 = __shfl_down(owner, off);
        if (v2 < m || (v2 == m && i2 < mi)) { m = v2; mi = i2; owner = o2; }
      }
      int wi = __shfl(mi, 0);
      int wo = __shfl(owner, 0);
      if (lane == 0 && wi >= 0 && wi < N) {
        // count in high 16 bits; sum of g in low 16 (exact g when count==1)
        atomicAdd(&packed[wi], (1u << 16) | (u32)g);
      }
      if (lane == wo) { v = 1e30f; idx = INT_MAX; }  // consume
    }
  }
}

// Phase 3: resolve every anchor. cnt 0/1 inline; cnt>1 handled
// wave-cooperatively (all 64 lanes argmin 128 g's for each multi anchor).
__global__ __launch_bounds__(TPB) void k_phase3(
    const float* pred, const float* priors, const float* dec,
    const float* gtb, const int* gtl, const float* sumL1,
    const u8* validArr, const u32* packed,
    float* out, int N, int G, int C, int Nout)
{
  __shared__ float sg[MAXG * 4];
  __shared__ int sl[MAXG];
  for (int i = threadIdx.x; i < G * 4; i += blockDim.x) sg[i] = gtb[i];
  for (int i = threadIdx.x; i < G; i += blockDim.x) {
    int lb = gtl[i];
    if (lb < 0) lb = 0;
    if (lb >= C) lb = C - 1;
    sl[i] = lb;
  }
  __syncthreads();
  const int tid = threadIdx.x;
  const int lane = tid & 63;
  const float4* dec4 = reinterpret_cast<const float4*>(dec);
  const float4* pri4 = reinterpret_cast<const float4*>(priors);
  int n = blockIdx.x * TPB + tid;
  bool active = (n < N && n < Nout);
  u32 pk = active ? packed[n] : 0;
  int cnt = (int)(pk >> 16);

  if (active && cnt <= 1) {
    float o0 = 0.0f, o1 = -1.0f, o2 = -100000.0f;
    if (cnt == 1) {
      int g = (int)(pk & 0xFFFFu);
      if (g < 0) g = 0;
      if (g >= G) g = G - 1;
      float4 d = dec4[n];
      float x0 = sg[g * 4 + 0], y0 = sg[g * 4 + 1], x1 = sg[g * 4 + 2], y1 = sg[g * 4 + 3];
      float iou = f_iou(d.x, d.y, d.z, d.w, x0, y0, x1, y1);
      if (!validArr[n]) iou = 0.0f;
      o0 = (float)g; o1 = 1.0f; o2 = iou;
    }
    out[n]            = o0;
    out[Nout + n]     = o1;
    out[2 * Nout + n] = o2;
  }

  // wave-cooperative multi-match: argmin over full cost row == np.argmin
  u64 mm = __ballot(active && cnt > 1);
  while (mm) {
    int l = (int)(__ffsll((unsigned long long)mm) - 1);
    mm &= mm - 1;
    int mn = __shfl(n, l);
    float4 dvb = dec4[mn];
    float4 pv = pri4[mn];
    float s1 = sumL1[mn];
    int vld = validArr[mn];
    float best = 1e30f; int bg = INT_MAX;
    for (int gg = lane; gg < G; gg += 64) {
      float x0 = sg[gg * 4 + 0], y0 = sg[gg * 4 + 1];
      float x1 = sg[gg * 4 + 2], y1 = sg[gg * 4 + 3];
      float iou = f_iou(dvb.x, dvb.y, dvb.z, dvb.w, x0, y0, x1, y1);
      if (!vld) iou = 0.0f;
      float dv = f_dv(pred[(size_t)mn * C + sl[gg]]);
      float c = f_cost(iou, dv, s1, pv.x, pv.y, pv.z, pv.w, x0, y0, x1, y1, vld);
      if (c < best || (c == best && gg < bg)) { best = c; bg = gg; }
    }
#pragma unroll
    for (int off = 32; off > 0; off >>= 1) {
      float v2 = __shfl_down(best, off);
      int g2 = __shfl_down(bg, off);
      if (v2 < best || (v2 == best && g2 < bg)) { best = v2; bg = g2; }
    }
    int wg = __shfl(bg, 0);
    if (lane == 0) {
      int g = (wg < 0 || wg >= G) ? 0 : wg;
      float x0 = sg[g * 4 + 0], y0 = sg[g * 4 + 1];
      float x1 = sg[g * 4 + 2], y1 = sg[g * 4 + 3];
      float iou = f_iou(dvb.x, dvb.y, dvb.z, dvb.w, x0, y0, x1, y1);
      if (!vld) iou = 0.0f;
      out[mn]            = (float)g;
      out[Nout + mn]     = 1.0f;
      out[2 * Nout + mn] = iou;
    }
  }
}

extern "C" void kernel_launch(void* const* d_in, const int* in_sizes, int n_in,
                              void* d_out, int out_size, void* d_ws, size_t ws_size,
                              hipStream_t stream) {
  const float* pred   = (const float*)d_in[0];  // (N,C) f32
  const float* priors = (const float*)d_in[1];  // (N,4) f32
  const float* dec    = (const float*)d_in[2];  // (N,4) f32
  const float* gtb    = (const float*)d_in[3];  // (G,4) f32
  const int*   gtl    = (const int*)d_in[4];    // (G,)  int32
  int N = in_sizes[2] / 4;
  int G = in_sizes[3] / 4;
  int C = in_sizes[0] / N;
  int Nout = out_size / 3;
  float* out = (float*)d_out;

  dim3 b(TPB);
  int oblk = (Nout + TPB - 1) / TPB;
  int chunk = (N + GSPLIT - 1) / GSPLIT;
  if (G > MAXG || chunk > GSLICE) {
    k_fb<<<oblk, b, 0, stream>>>(out, Nout, -60000.0f);  // static caps exceeded
    return;
  }

  // ws layout (16B-aligned): packed u32[N] | sumL1 f32[N] | valid u8[N] |
  // gateCnt2 i32[G*GSPLIT] | gateList i32[G*GSPLIT*GSLICE]
  size_t offPacked = 0;
  size_t offSum    = offPacked + (size_t)N * 4;
  size_t offValid  = offSum + (size_t)N * 4;
  size_t offCnt2   = (offValid + (size_t)N + 15) & ~(size_t)15;
  size_t offGlist  = (offCnt2 + (size_t)G * GSPLIT * 4 + 15) & ~(size_t)15;
  size_t need      = offGlist + (size_t)G * GSPLIT * GSLICE * 4;
  if (ws_size < need || d_ws == nullptr) {
    k_fb<<<oblk, b, 0, stream>>>(out, Nout, -70000.0f);
    return;
  }
  char* wsb = (char*)d_ws;
  u32* packed   = (u32*)(wsb + offPacked);
  float* sumL1  = (float*)(wsb + offSum);
  u8* validArr  = (u8*)(wsb + offValid);
  int* gateCnt2 = (int*)(wsb + offCnt2);
  int* gateList = (int*)(wsb + offGlist);

  int sumBlocks = (N * 8 + TPB - 1) / TPB;
  int nblk = (N + TPB - 1) / TPB;
  k_phase1<<<sumBlocks + G * GSPLIT, b, 0, stream>>>(
      pred, priors, gtb, sumL1, packed, validArr, gateCnt2, gateList,
      N, G, C, sumBlocks);
  k_phase2<<<G, b, 0, stream>>>(
      pred, priors, dec, gtb, gtl, sumL1, validArr, gateCnt2, gateList,
      packed, N, G, C);
  k_phase3<<<nblk, b, 0, stream>>>(
      pred, priors, dec, gtb, gtl, sumL1, validArr, packed,
      out, N, G, C, Nout);
}

// Round 14
// 134.998 us; speedup vs baseline: 3.1353x; 1.2941x over previous
//
#include <hip/hip_runtime.h>
#include <math.h>
#include <limits.h>

// Match numpy op-for-op: no fma contraction anywhere.
#pragma clang fp contract(off)

#define TPB 256
#define ATPB 64
#define KTOP 10
#define ISPLIT 64     // iou-scan splits per gt (8192 one-wave blocks)
#define GSPLIT 8
#define GSLICE 4352   // per-(g,chunk) list capacity; >= ceil(N/GSPLIT) guarded on host
#define MAXG 512

typedef unsigned int u32;
typedef unsigned long long u64;
typedef unsigned char u8;

// pairwise IoU, identical op order to the numpy reference
__device__ __forceinline__ float f_iou(float ax0, float ay0, float ax1, float ay1,
                                       float bx0, float by0, float bx1, float by1) {
  float tlx = fmaxf(ax0, bx0);
  float tly = fmaxf(ay0, by0);
  float brx = fminf(ax1, bx1);
  float bry = fminf(ay1, by1);
  float w = fmaxf(brx - tlx, 0.0f);
  float h = fmaxf(bry - tly, 0.0f);
  float inter = w * h;
  float aa = fmaxf(ax1 - ax0, 0.0f) * fmaxf(ay1 - ay0, 0.0f);
  float ab = fmaxf(bx1 - bx0, 0.0f) * fmaxf(by1 - by0, 0.0f);
  float uni = aa + ab - inter;
  return inter / fmaxf(uni, 1e-7f);
}

// dv = -(L - L1), exact expression tree of the reference cls numerator
__device__ __forceinline__ float f_dv(float p) {
  float L  = fmaxf(logf(p), -100.0f);
  float L1 = fmaxf(log1pf(-p), -100.0f);
  return -(L - L1);
}

// full cost(n,g); identical op order to reference (cls = dv - sumL1).
__device__ __forceinline__ float f_cost(float iou_masked, float dv, float sumL1v,
                                        float px, float py, float sx, float sy,
                                        float bx0, float by0, float bx1, float by1,
                                        int vld) {
  if (!vld) return 100000000.0f;  // BIG
  float cls = dv - sumL1v;
  float l_ = px - bx0, t_ = py - by0, r_ = bx1 - px, b_ = by1 - py;
  bool ing = fminf(fminf(l_, t_), fminf(r_, b_)) > 0.0f;
  float gcx = (bx0 + bx1) * 0.5f;
  float gcy = (by0 + by1) * 0.5f;
  float cl = px - (gcx - 2.5f * sx);
  float ct = py - (gcy - 2.5f * sy);
  float cr = (gcx + 2.5f * sx) - px;
  float cb = (gcy + 2.5f * sy) - py;
  bool inc = fminf(fminf(cl, ct), fminf(cr, cb)) > 0.0f;
  float icost = -logf(iou_masked + 1e-7f);
  return (cls * 1.0f + icost * 3.0f) + ((ing && inc) ? 0.0f : 100000.0f);
}

// Sentinel fallback: -70000 (ws too small) / -60000 (shape exceeds static caps)
__global__ __launch_bounds__(TPB) void k_fb(float* out, int Nout, float val) {
  int n = blockIdx.x * blockDim.x + threadIdx.x;
  if (n >= Nout) return;
  out[n] = 0.0f;
  out[Nout + n] = -1.0f;
  out[2 * Nout + n] = val;
}

// Phase 1: blocks [0, sumBlocks) — per-anchor sumL1 + valid flag + packed=0
// (all written unconditionally; no init assumptions). Blocks [sumBlocks, ...)
// — gating for one (g, chunk): LDS-compacted gated list written to a PRIVATE
// per-(g,chunk) slice + count. No global atomics anywhere.
__global__ __launch_bounds__(TPB) void k_phase1(
    const float* pred, const float* priors, const float* gtb,
    float* sumL1, u32* packed, u8* validArr,
    int* gateCnt2, int* gateList,
    int N, int G, int C, int sumBlocks)
{
  __shared__ float sg[MAXG * 4];
  __shared__ int lbuf[GSLICE];
  __shared__ int lcnt;
  const int tid = threadIdx.x;
  const int lane = tid & 63;
  const float4* pri4 = reinterpret_cast<const float4*>(priors);

  if ((int)blockIdx.x < sumBlocks) {
    // ---- sum role: 8 lanes per anchor ----
    for (int i = tid; i < G * 4; i += TPB) sg[i] = gtb[i];
    __syncthreads();
    int t = blockIdx.x * TPB + tid;
    int n = t >> 3, j = t & 7;
    if (n >= N) return;  // whole 8-lane groups exit together
    float4 pv = pri4[n];
    float px = pv.x, py = pv.y, sx = pv.z, sy = pv.w;
    // valid = OR over g of (in_box || in_center); lane j owns g ≡ j (mod 8)
    int valid = 0;
    for (int g = j; g < G; g += 8) {
      float x0 = sg[g * 4 + 0], y0 = sg[g * 4 + 1], x1 = sg[g * 4 + 2], y1 = sg[g * 4 + 3];
      float l_ = px - x0, t_ = py - y0, r_ = x1 - px, b_ = y1 - py;
      bool ing = fminf(fminf(l_, t_), fminf(r_, b_)) > 0.0f;
      float gcx = (x0 + x1) * 0.5f, gcy = (y0 + y1) * 0.5f;
      float cl = px - (gcx - 2.5f * sx), ct = py - (gcy - 2.5f * sy);
      float cr = (gcx + 2.5f * sx) - px, cb = (gcy + 2.5f * sy) - py;
      bool inc = fminf(fminf(cl, ct), fminf(cr, cb)) > 0.0f;
      valid |= (ing || inc) ? 1 : 0;
    }
    valid |= __shfl_xor(valid, 1, 8);
    valid |= __shfl_xor(valid, 2, 8);
    valid |= __shfl_xor(valid, 4, 8);
    // sumL1: lane j owns classes i ≡ j (mod 8) ascending == numpy 8-acc
    // pairwise order; shfl tree == ((r0+r1)+(r2+r3))+((r4+r5)+(r6+r7)).
    const float* pr = pred + (size_t)n * C;
    int lim = C - (C % 8);
    float r = 0.0f;
    for (int i = j; i < lim; i += 8) r += fmaxf(log1pf(-pr[i]), -100.0f);
    r += __shfl_down(r, 1, 8);
    r += __shfl_down(r, 2, 8);
    r += __shfl_down(r, 4, 8);
    if (j == 0) {
      for (int i = lim; i < C; ++i) r += fmaxf(log1pf(-pr[i]), -100.0f);
      sumL1[n] = r;
      validArr[n] = (u8)valid;  // unconditional: every n written exactly once
      packed[n] = 0;            // ws re-poisoned every launch — must re-zero
    }
    return;
  }

  // ---- gate role ----
  int bidg = blockIdx.x - sumBlocks;
  int g = bidg / GSPLIT, s = bidg % GSPLIT;
  int chunk = (N + GSPLIT - 1) / GSPLIT;  // host guarantees chunk <= GSLICE
  int start = s * chunk;
  int end = start + chunk; if (end > N) end = N;
  float x0 = gtb[g * 4 + 0], y0 = gtb[g * 4 + 1];
  float x1 = gtb[g * 4 + 2], y1 = gtb[g * 4 + 3];
  float gcx = (x0 + x1) * 0.5f, gcy = (y0 + y1) * 0.5f;
  if (tid == 0) lcnt = 0;
  __syncthreads();
  for (int nb = start; nb < end; nb += TPB) {
    int n = nb + tid;
    bool gated = false;
    if (n < end) {
      float4 pv = pri4[n];
      float px = pv.x, py = pv.y, sx = pv.z, sy = pv.w;
      float l_ = px - x0, t_ = py - y0, r_ = x1 - px, b_ = y1 - py;
      bool ing = fminf(fminf(l_, t_), fminf(r_, b_)) > 0.0f;
      float cl = px - (gcx - 2.5f * sx), ct = py - (gcy - 2.5f * sy);
      float cr = (gcx + 2.5f * sx) - px, cb = (gcy + 2.5f * sy) - py;
      bool inc = fminf(fminf(cl, ct), fminf(cr, cb)) > 0.0f;
      gated = ing && inc;
    }
    u64 mask = __ballot(gated);
    int wcnt = __popcll(mask);
    int wbase = 0;
    if (lane == 0 && wcnt > 0) wbase = atomicAdd(&lcnt, wcnt);  // LDS atomic only
    wbase = __shfl(wbase, 0);
    if (gated) {
      int p = __popcll(mask & ((1ull << lane) - 1ull));
      lbuf[wbase + p] = n;  // lcnt <= chunk <= GSLICE: no overflow possible
    }
  }
  __syncthreads();
  int total = lcnt;
  if (tid == 0) gateCnt2[bidg] = total;  // written exactly once — no zero-init
  int* gl = gateList + (size_t)bidg * GSLICE;
  for (int i = tid; i < total; i += TPB) gl[i] = lbuf[i];
}

// Phase 2a: ONE WAVE per (g, split), ISPLIT=64 -> 8192 waves (full machine).
// Only iv[10] live; zero-init (iou>=0; zero-pad sum-invariant) so the ~95%
// of zero-iou pairs skip the insert entirely.
__global__ __launch_bounds__(ATPB) void k_iou_part(
    const float* dec, const u8* validArr, const float* gtb,
    float* iouV, int N, int G)
{
  int bid = blockIdx.x;
  int g = bid / ISPLIT;
  int s = bid % ISPLIT;
  int chunk = (N + ISPLIT - 1) / ISPLIT;
  int start = s * chunk;
  int end = start + chunk; if (end > N) end = N;
  int tid = threadIdx.x;
  float bx0 = gtb[g * 4 + 0];
  float by0 = gtb[g * 4 + 1];
  float bx1 = gtb[g * 4 + 2];
  float by1 = gtb[g * 4 + 3];

  float iv[KTOP];
#pragma unroll
  for (int j = 0; j < KTOP; ++j) iv[j] = 0.0f;

  const float4* dec4 = reinterpret_cast<const float4*>(dec);
  for (int n = start + tid; n < end; n += ATPB) {
    float4 dvb = dec4[n];
    float iou = f_iou(dvb.x, dvb.y, dvb.z, dvb.w, bx0, by0, bx1, by1);
    if (!validArr[n]) iou = 0.0f;
    if (iou > iv[KTOP - 1]) {
      float cu = iou;
#pragma unroll
      for (int j = 0; j < KTOP; ++j) {
        if (cu > iv[j]) { float tv = iv[j]; iv[j] = cu; cu = tv; }
      }
    }
  }

  // wave tournament: 10 rounds of max + owner pop (values only)
#pragma unroll
  for (int r = 0; r < KTOP; ++r) {
    float v = iv[0]; int owner = tid;
#pragma unroll
    for (int off = 32; off > 0; off >>= 1) {
      float v2 = __shfl_down(v, off);
      int o2 = __shfl_down(owner, off);
      if (v2 > v || (v2 == v && o2 < owner)) { v = v2; owner = o2; }
    }
    float wv = __shfl(v, 0);
    int wo = __shfl(owner, 0);
    if (tid == 0) iouV[bid * KTOP + r] = wv;
    if (tid == wo) {
#pragma unroll
      for (int j = 0; j < KTOP - 1; ++j) iv[j] = iv[j + 1];
      iv[KTOP - 1] = 0.0f;
    }
  }
}

// Phase 2b: one WAVE (64-thread block) per g. (a) top-10 of ISPLIT*10 iou
// values -> dynamic_k; (b) cost top-10 over gated candidates (strictly below
// any ungated/invalid cost when total >= 10; else exact full scan), scatter.
// Lexicographic (cost,n) everywhere -> order-independent & stable.
__global__ __launch_bounds__(ATPB) void k_merge(
    const float* iouV, const int* gateCnt2, const int* gateList,
    const float* pred, const float* priors, const float* dec, const float* sumL1,
    const u8* validArr, const int* gtl, const float* gtb,
    u32* packed, int G, int N, int C)
{
  int g = blockIdx.x;
  int tid = threadIdx.x;
  int base = g * ISPLIT * KTOP;
  const int TOT = ISPLIT * KTOP;            // 640
  const int PER = TOT / ATPB;               // 10

  // --- dynamic_k from iou top-10 of TOT values (zero-padded; sum invariant) ---
  float il[PER];
#pragma unroll
  for (int k = 0; k < PER; ++k) il[k] = 0.0f;
#pragma unroll
  for (int k = 0; k < PER; ++k) {
    float v = iouV[base + tid + k * ATPB];
    if (v > il[PER - 1]) {
#pragma unroll
      for (int j = 0; j < PER; ++j) {
        if (v > il[j]) { float tv = il[j]; il[j] = v; v = tv; }
      }
    }
  }
  float rv[KTOP];
#pragma unroll
  for (int r = 0; r < KTOP; ++r) {
    float v = il[0]; int owner = tid;
#pragma unroll
    for (int off = 32; off > 0; off >>= 1) {
      float v2 = __shfl_down(v, off);
      int o2 = __shfl_down(owner, off);
      if (v2 > v || (v2 == v && o2 < owner)) { v = v2; owner = o2; }
    }
    float wv = __shfl(v, 0);
    int wo = __shfl(owner, 0);
    rv[r] = wv;
    if (tid == wo) {
#pragma unroll
      for (int j = 0; j < PER - 1; ++j) il[j] = il[j + 1];
      il[PER - 1] = 0.0f;
    }
  }
  // numpy pairwise order for a 10-element sum (all lanes identical)
  float s8 = ((rv[0] + rv[1]) + (rv[2] + rv[3])) + ((rv[4] + rv[5]) + (rv[6] + rv[7]));
  s8 += rv[8];
  s8 += rv[9];
  int dk = (int)s8;  // trunc toward zero == astype(int32)
  if (dk < 1) dk = 1;
  if (dk > KTOP) dk = KTOP;

  float bx0 = gtb[g * 4 + 0], by0 = gtb[g * 4 + 1];
  float bx1 = gtb[g * 4 + 2], by1 = gtb[g * 4 + 3];
  int lab = gtl[g];
  if (lab < 0) lab = 0;
  if (lab >= C) lab = C - 1;

  float cv[KTOP]; int ci[KTOP];
#pragma unroll
  for (int j = 0; j < KTOP; ++j) { cv[j] = 1e30f; ci[j] = INT_MAX; }
  const float4* dec4 = reinterpret_cast<const float4*>(dec);

  int total = 0;
  for (int s = 0; s < GSPLIT; ++s) total += gateCnt2[g * GSPLIT + s];

  if (total >= KTOP) {
    // fast path: gated-only (gated cost strictly below ungated/invalid)
    for (int s = 0; s < GSPLIT; ++s) {
      int cs = gateCnt2[g * GSPLIT + s];
      const int* gl = gateList + (size_t)(g * GSPLIT + s) * GSLICE;
      for (int i = tid; i < cs; i += ATPB) {
        int n = gl[i];
        float4 d = dec4[n];
        float iou = f_iou(d.x, d.y, d.z, d.w, bx0, by0, bx1, by1);
        float dv = f_dv(pred[(size_t)n * C + lab]);
        float cls = dv - sumL1[n];
        float icost = -logf(iou + 1e-7f);
        float c = (cls * 1.0f + icost * 3.0f) + 0.0f;  // gate true -> +0 exactly
        bool ins = (c < cv[KTOP - 1]) || (c == cv[KTOP - 1] && n < ci[KTOP - 1]);
        if (ins) {
          float cu = c; int cui = n;
#pragma unroll
          for (int j = 0; j < KTOP; ++j) {
            bool lt = (cu < cv[j]) || (cu == cv[j] && cui < ci[j]);
            if (lt) { float tv = cv[j]; int ti = ci[j]; cv[j] = cu; ci[j] = cui; cu = tv; cui = ti; }
          }
        }
      }
    }
  } else {
    // exact full scan (rare: fewer than 10 gated anchors for this g)
    const float4* pri4 = reinterpret_cast<const float4*>(priors);
    for (int n = tid; n < N; n += ATPB) {
      float4 d = dec4[n];
      int vld = validArr[n];
      float iou = f_iou(d.x, d.y, d.z, d.w, bx0, by0, bx1, by1);
      if (!vld) iou = 0.0f;
      float dv = f_dv(pred[(size_t)n * C + lab]);
      float4 pv = pri4[n];
      float c = f_cost(iou, dv, sumL1[n], pv.x, pv.y, pv.z, pv.w,
                       bx0, by0, bx1, by1, vld);
      bool ins = (c < cv[KTOP - 1]) || (c == cv[KTOP - 1] && n < ci[KTOP - 1]);
      if (ins) {
        float cu = c; int cui = n;
#pragma unroll
        for (int j = 0; j < KTOP; ++j) {
          bool lt = (cu < cv[j]) || (cu == cv[j] && cui < ci[j]);
          if (lt) { float tv = cv[j]; int ti = ci[j]; cv[j] = cu; ci[j] = cui; cu = tv; cui = ti; }
        }
      }
    }
  }

  // wave tournament: dk rounds of lexicographic min, scatter
  for (int r = 0; r < KTOP; ++r) {
    float v = cv[0]; int idx = ci[0];
#pragma unroll
    for (int off = 32; off > 0; off >>= 1) {
      float v2 = __shfl_down(v, off);
      int i2 = __shfl_down(idx, off);
      if (v2 < v || (v2 == v && i2 < idx)) { v = v2; idx = i2; }
    }
    int wi = __shfl(idx, 0);
    if (r < dk && tid == 0 && wi >= 0 && wi < N) {
      // count in high 16 bits; sum of g in low 16 (exact g when count==1)
      atomicAdd(&packed[wi], (1u << 16) | (u32)g);
    }
    if (ci[0] == wi && wi != INT_MAX) {  // n unique per g -> one lane pops
#pragma unroll
      for (int j = 0; j < KTOP - 1; ++j) { cv[j] = cv[j + 1]; ci[j] = ci[j + 1]; }
      cv[KTOP - 1] = 1e30f; ci[KTOP - 1] = INT_MAX;
    }
    if (r + 1 >= dk) break;
  }
}

// Phase 3: resolve every anchor. cnt 0/1 inline; cnt>1 handled
// wave-cooperatively (all 64 lanes argmin 128 g's for each multi anchor).
__global__ __launch_bounds__(TPB) void k_phase3(
    const float* pred, const float* priors, const float* dec,
    const float* gtb, const int* gtl, const float* sumL1,
    const u8* validArr, const u32* packed,
    float* out, int N, int G, int C, int Nout)
{
  __shared__ float sg[MAXG * 4];
  __shared__ int sl[MAXG];
  for (int i = threadIdx.x; i < G * 4; i += blockDim.x) sg[i] = gtb[i];
  for (int i = threadIdx.x; i < G; i += blockDim.x) {
    int lb = gtl[i];
    if (lb < 0) lb = 0;
    if (lb >= C) lb = C - 1;
    sl[i] = lb;
  }
  __syncthreads();
  const int tid = threadIdx.x;
  const int lane = tid & 63;
  const float4* dec4 = reinterpret_cast<const float4*>(dec);
  const float4* pri4 = reinterpret_cast<const float4*>(priors);
  int n = blockIdx.x * TPB + tid;
  bool active = (n < N && n < Nout);
  u32 pk = active ? packed[n] : 0;
  int cnt = (int)(pk >> 16);

  if (active && cnt <= 1) {
    float o0 = 0.0f, o1 = -1.0f, o2 = -100000.0f;
    if (cnt == 1) {
      int g = (int)(pk & 0xFFFFu);
      if (g < 0) g = 0;
      if (g >= G) g = G - 1;
      float4 d = dec4[n];
      float x0 = sg[g * 4 + 0], y0 = sg[g * 4 + 1], x1 = sg[g * 4 + 2], y1 = sg[g * 4 + 3];
      float iou = f_iou(d.x, d.y, d.z, d.w, x0, y0, x1, y1);
      if (!validArr[n]) iou = 0.0f;
      o0 = (float)g; o1 = 1.0f; o2 = iou;
    }
    out[n]            = o0;
    out[Nout + n]     = o1;
    out[2 * Nout + n] = o2;
  }

  // wave-cooperative multi-match: argmin over full cost row == np.argmin
  u64 mm = __ballot(active && cnt > 1);
  while (mm) {
    int l = (int)(__ffsll((unsigned long long)mm) - 1);
    mm &= mm - 1;
    int mn = __shfl(n, l);
    float4 dvb = dec4[mn];
    float4 pv = pri4[mn];
    float s1 = sumL1[mn];
    int vld = validArr[mn];
    float best = 1e30f; int bg = INT_MAX;
    for (int gg = lane; gg < G; gg += 64) {
      float x0 = sg[gg * 4 + 0], y0 = sg[gg * 4 + 1];
      float x1 = sg[gg * 4 + 2], y1 = sg[gg * 4 + 3];
      float iou = f_iou(dvb.x, dvb.y, dvb.z, dvb.w, x0, y0, x1, y1);
      if (!vld) iou = 0.0f;
      float dv = f_dv(pred[(size_t)mn * C + sl[gg]]);
      float c = f_cost(iou, dv, s1, pv.x, pv.y, pv.z, pv.w, x0, y0, x1, y1, vld);
      if (c < best || (c == best && gg < bg)) { best = c; bg = gg; }
    }
#pragma unroll
    for (int off = 32; off > 0; off >>= 1) {
      float v2 = __shfl_down(best, off);
      int g2 = __shfl_down(bg, off);
      if (v2 < best || (v2 == best && g2 < bg)) { best = v2; bg = g2; }
    }
    int wg = __shfl(bg, 0);
    if (lane == 0) {
      int g = (wg < 0 || wg >= G) ? 0 : wg;
      float x0 = sg[g * 4 + 0], y0 = sg[g * 4 + 1];
      float x1 = sg[g * 4 + 2], y1 = sg[g * 4 + 3];
      float iou = f_iou(dvb.x, dvb.y, dvb.z, dvb.w, x0, y0, x1, y1);
      if (!vld) iou = 0.0f;
      out[mn]            = (float)g;
      out[Nout + mn]     = 1.0f;
      out[2 * Nout + mn] = iou;
    }
  }
}

extern "C" void kernel_launch(void* const* d_in, const int* in_sizes, int n_in,
                              void* d_out, int out_size, void* d_ws, size_t ws_size,
                              hipStream_t stream) {
  const float* pred   = (const float*)d_in[0];  // (N,C) f32
  const float* priors = (const float*)d_in[1];  // (N,4) f32
  const float* dec    = (const float*)d_in[2];  // (N,4) f32
  const float* gtb    = (const float*)d_in[3];  // (G,4) f32
  const int*   gtl    = (const int*)d_in[4];    // (G,)  int32
  int N = in_sizes[2] / 4;
  int G = in_sizes[3] / 4;
  int C = in_sizes[0] / N;
  int Nout = out_size / 3;
  float* out = (float*)d_out;

  dim3 b(TPB);
  int oblk = (Nout + TPB - 1) / TPB;
  int chunk = (N + GSPLIT - 1) / GSPLIT;
  if (G > MAXG || chunk > GSLICE) {
    k_fb<<<oblk, b, 0, stream>>>(out, Nout, -60000.0f);  // static caps exceeded
    return;
  }

  // ws layout (16B-aligned): packed u32[N] | sumL1 f32[N] | valid u8[N] |
  // gateCnt2 i32[G*GSPLIT] | gateList i32[G*GSPLIT*GSLICE] | iouV f32[G*ISPLIT*10]
  size_t offPacked = 0;
  size_t offSum    = offPacked + (size_t)N * 4;
  size_t offValid  = offSum + (size_t)N * 4;
  size_t offCnt2   = (offValid + (size_t)N + 15) & ~(size_t)15;
  size_t offGlist  = (offCnt2 + (size_t)G * GSPLIT * 4 + 15) & ~(size_t)15;
  size_t offIouV   = offGlist + (size_t)G * GSPLIT * GSLICE * 4;
  size_t need      = offIouV + (size_t)G * ISPLIT * KTOP * 4;
  if (ws_size < need || d_ws == nullptr) {
    k_fb<<<oblk, b, 0, stream>>>(out, Nout, -70000.0f);
    return;
  }
  char* wsb = (char*)d_ws;
  u32* packed   = (u32*)(wsb + offPacked);
  float* sumL1  = (float*)(wsb + offSum);
  u8* validArr  = (u8*)(wsb + offValid);
  int* gateCnt2 = (int*)(wsb + offCnt2);
  int* gateList = (int*)(wsb + offGlist);
  float* iouV   = (float*)(wsb + offIouV);

  int sumBlocks = (N * 8 + TPB - 1) / TPB;
  int nblk = (N + TPB - 1) / TPB;
  k_phase1<<<sumBlocks + G * GSPLIT, b, 0, stream>>>(
      pred, priors, gtb, sumL1, packed, validArr, gateCnt2, gateList,
      N, G, C, sumBlocks);
  k_iou_part<<<G * ISPLIT, dim3(ATPB), 0, stream>>>(dec, validArr, gtb, iouV, N, G);
  k_merge<<<G, dim3(ATPB), 0, stream>>>(
      iouV, gateCnt2, gateList, pred, priors, dec, sumL1, validArr, gtl, gtb,
      packed, G, N, C);
  k_phase3<<<nblk, b, 0, stream>>>(
      pred, priors, dec, gtb, gtl, sumL1, validArr, packed,
      out, N, G, C, Nout);
}

// Round 15
// 129.150 us; speedup vs baseline: 3.2773x; 1.0453x over previous
//
#include <hip/hip_runtime.h>
#include <math.h>
#include <limits.h>

// Match numpy op-for-op: no fma contraction anywhere.
#pragma clang fp contract(off)

#define TPB 256
#define ATPB 64
#define KTOP 10
#define ISPLIT 64     // iou-scan splits per gt (8192 waves)
#define GSPLIT 8
#define GSLICE 4352   // per-(g,chunk) list capacity; >= ceil(N/GSPLIT) guarded on host
#define MAXG 512

typedef unsigned int u32;
typedef unsigned long long u64;
typedef unsigned char u8;

// pairwise IoU, identical op order to the numpy reference
__device__ __forceinline__ float f_iou(float ax0, float ay0, float ax1, float ay1,
                                       float bx0, float by0, float bx1, float by1) {
  float tlx = fmaxf(ax0, bx0);
  float tly = fmaxf(ay0, by0);
  float brx = fminf(ax1, bx1);
  float bry = fminf(ay1, by1);
  float w = fmaxf(brx - tlx, 0.0f);
  float h = fmaxf(bry - tly, 0.0f);
  float inter = w * h;
  float aa = fmaxf(ax1 - ax0, 0.0f) * fmaxf(ay1 - ay0, 0.0f);
  float ab = fmaxf(bx1 - bx0, 0.0f) * fmaxf(by1 - by0, 0.0f);
  float uni = aa + ab - inter;
  return inter / fmaxf(uni, 1e-7f);
}

// dv = -(L - L1), exact expression tree of the reference cls numerator
__device__ __forceinline__ float f_dv(float p) {
  float L  = fmaxf(logf(p), -100.0f);
  float L1 = fmaxf(log1pf(-p), -100.0f);
  return -(L - L1);
}

// full cost(n,g); identical op order to reference (cls = dv - sumL1).
__device__ __forceinline__ float f_cost(float iou_masked, float dv, float sumL1v,
                                        float px, float py, float sx, float sy,
                                        float bx0, float by0, float bx1, float by1,
                                        int vld) {
  if (!vld) return 100000000.0f;  // BIG
  float cls = dv - sumL1v;
  float l_ = px - bx0, t_ = py - by0, r_ = bx1 - px, b_ = by1 - py;
  bool ing = fminf(fminf(l_, t_), fminf(r_, b_)) > 0.0f;
  float gcx = (bx0 + bx1) * 0.5f;
  float gcy = (by0 + by1) * 0.5f;
  float cl = px - (gcx - 2.5f * sx);
  float ct = py - (gcy - 2.5f * sy);
  float cr = (gcx + 2.5f * sx) - px;
  float cb = (gcy + 2.5f * sy) - py;
  bool inc = fminf(fminf(cl, ct), fminf(cr, cb)) > 0.0f;
  float icost = -logf(iou_masked + 1e-7f);
  return (cls * 1.0f + icost * 3.0f) + ((ing && inc) ? 0.0f : 100000.0f);
}

// Sentinel fallback: -70000 (ws too small) / -60000 (shape exceeds static caps)
__global__ __launch_bounds__(TPB) void k_fb(float* out, int Nout, float val) {
  int n = blockIdx.x * blockDim.x + threadIdx.x;
  if (n >= Nout) return;
  out[n] = 0.0f;
  out[Nout + n] = -1.0f;
  out[2 * Nout + n] = val;
}

// D1: blocks [0, valBlocks) — per-anchor valid flag (8 lanes/anchor OR over g;
// exclusive ownership, no races). Blocks [valBlocks, ...) — gating for one
// (g, chunk): LDS-compacted gated list -> PRIVATE per-(g,chunk) slice + count.
// No global atomics anywhere.
__global__ __launch_bounds__(TPB) void k_prep(
    const float* priors, const float* gtb,
    u8* validArr, int* gateCnt2, int* gateList,
    int N, int G, int valBlocks)
{
  const int tid = threadIdx.x;
  const int lane = tid & 63;
  const float4* pri4 = reinterpret_cast<const float4*>(priors);

  if ((int)blockIdx.x < valBlocks) {
    // ---- valid role: 8 lanes per anchor, OR over g ≡ j (mod 8) ----
    __shared__ float sg[MAXG * 4];
    for (int i = tid; i < G * 4; i += TPB) sg[i] = gtb[i];
    __syncthreads();
    int t = blockIdx.x * TPB + tid;
    int n = t >> 3, j = t & 7;
    if (n >= N) return;  // whole 8-lane groups exit together
    float4 pv = pri4[n];
    float px = pv.x, py = pv.y, sx = pv.z, sy = pv.w;
    int valid = 0;
    for (int g = j; g < G; g += 8) {
      float x0 = sg[g * 4 + 0], y0 = sg[g * 4 + 1], x1 = sg[g * 4 + 2], y1 = sg[g * 4 + 3];
      float l_ = px - x0, t_ = py - y0, r_ = x1 - px, b_ = y1 - py;
      bool ing = fminf(fminf(l_, t_), fminf(r_, b_)) > 0.0f;
      float gcx = (x0 + x1) * 0.5f, gcy = (y0 + y1) * 0.5f;
      float cl = px - (gcx - 2.5f * sx), ct = py - (gcy - 2.5f * sy);
      float cr = (gcx + 2.5f * sx) - px, cb = (gcy + 2.5f * sy) - py;
      bool inc = fminf(fminf(cl, ct), fminf(cr, cb)) > 0.0f;
      valid |= (ing || inc) ? 1 : 0;
    }
    valid |= __shfl_xor(valid, 1, 8);
    valid |= __shfl_xor(valid, 2, 8);
    valid |= __shfl_xor(valid, 4, 8);
    if (j == 0) validArr[n] = (u8)valid;  // every n written exactly once
    return;
  }

  // ---- gate role ----
  __shared__ int lbuf[GSLICE];
  __shared__ int lcnt;
  int bidg = blockIdx.x - valBlocks;
  int g = bidg / GSPLIT, s = bidg % GSPLIT;
  int chunk = (N + GSPLIT - 1) / GSPLIT;  // host guarantees chunk <= GSLICE
  int start = s * chunk;
  int end = start + chunk; if (end > N) end = N;
  float x0 = gtb[g * 4 + 0], y0 = gtb[g * 4 + 1];
  float x1 = gtb[g * 4 + 2], y1 = gtb[g * 4 + 3];
  float gcx = (x0 + x1) * 0.5f, gcy = (y0 + y1) * 0.5f;
  if (tid == 0) lcnt = 0;
  __syncthreads();
  for (int nb = start; nb < end; nb += TPB) {
    int n = nb + tid;
    bool gated = false;
    if (n < end) {
      float4 pv = pri4[n];
      float px = pv.x, py = pv.y, sx = pv.z, sy = pv.w;
      float l_ = px - x0, t_ = py - y0, r_ = x1 - px, b_ = y1 - py;
      bool ing = fminf(fminf(l_, t_), fminf(r_, b_)) > 0.0f;
      float cl = px - (gcx - 2.5f * sx), ct = py - (gcy - 2.5f * sy);
      float cr = (gcx + 2.5f * sx) - px, cb = (gcy + 2.5f * sy) - py;
      bool inc = fminf(fminf(cl, ct), fminf(cr, cb)) > 0.0f;
      gated = ing && inc;
    }
    u64 mask = __ballot(gated);
    int wcnt = __popcll(mask);
    int wbase = 0;
    if (lane == 0 && wcnt > 0) wbase = atomicAdd(&lcnt, wcnt);  // LDS atomic only
    wbase = __shfl(wbase, 0);
    if (gated) {
      int p = __popcll(mask & ((1ull << lane) - 1ull));
      lbuf[wbase + p] = n;  // lcnt <= chunk <= GSLICE: no overflow possible
    }
  }
  __syncthreads();
  int total = lcnt;
  if (tid == 0) gateCnt2[bidg] = total;  // written exactly once — no zero-init
  int* gl = gateList + (size_t)bidg * GSLICE;
  for (int i = tid; i < total; i += TPB) gl[i] = lbuf[i];
}

// D2: blocks [0, sumBlocks) — per-anchor sumL1 (numpy 8-acc pairwise order)
// + packed=0 (HBM-streaming role). Blocks [sumBlocks, ...) — 4 iou-scan
// waves per block, each wave owns one (g, split) unit (L2-bound role).
// Complementary resources run concurrently in one dispatch.
__global__ __launch_bounds__(TPB) void k_sumiou(
    const float* pred, const float* dec, const u8* validArr, const float* gtb,
    float* sumL1, u32* packed, float* iouV,
    int N, int G, int C, int sumBlocks)
{
  const int tid = threadIdx.x;
  const int lane = tid & 63;
  const int wid = tid >> 6;

  if ((int)blockIdx.x < sumBlocks) {
    int t = blockIdx.x * TPB + tid;
    int n = t >> 3, j = t & 7;
    if (n >= N) return;
    const float* pr = pred + (size_t)n * C;
    int lim = C - (C % 8);
    float r = 0.0f;
    for (int i = j; i < lim; i += 8) r += fmaxf(log1pf(-pr[i]), -100.0f);
    r += __shfl_down(r, 1, 8);
    r += __shfl_down(r, 2, 8);
    r += __shfl_down(r, 4, 8);
    if (j == 0) {
      for (int i = lim; i < C; ++i) r += fmaxf(log1pf(-pr[i]), -100.0f);
      sumL1[n] = r;
      packed[n] = 0;  // ws re-poisoned every launch — must re-zero
    }
    return;
  }

  int unit = ((int)blockIdx.x - sumBlocks) * 4 + wid;
  if (unit >= G * ISPLIT) return;
  int g = unit / ISPLIT, s = unit % ISPLIT;
  int chunk = (N + ISPLIT - 1) / ISPLIT;
  int start = s * chunk;
  int end = start + chunk; if (end > N) end = N;
  float bx0 = gtb[g * 4 + 0], by0 = gtb[g * 4 + 1];
  float bx1 = gtb[g * 4 + 2], by1 = gtb[g * 4 + 3];

  float iv[KTOP];
#pragma unroll
  for (int j = 0; j < KTOP; ++j) iv[j] = 0.0f;  // iou>=0; zero-pad sum-invariant

  const float4* dec4 = reinterpret_cast<const float4*>(dec);
  for (int n = start + lane; n < end; n += 64) {
    float4 dvb = dec4[n];
    float iou = f_iou(dvb.x, dvb.y, dvb.z, dvb.w, bx0, by0, bx1, by1);
    if (!validArr[n]) iou = 0.0f;
    if (iou > iv[KTOP - 1]) {
      float cu = iou;
#pragma unroll
      for (int j = 0; j < KTOP; ++j) {
        if (cu > iv[j]) { float tv = iv[j]; iv[j] = cu; cu = tv; }
      }
    }
  }

  // wave tournament: 10 rounds of max + owner pop (values only)
#pragma unroll
  for (int r = 0; r < KTOP; ++r) {
    float v = iv[0]; int owner = lane;
#pragma unroll
    for (int off = 32; off > 0; off >>= 1) {
      float v2 = __shfl_down(v, off);
      int o2 = __shfl_down(owner, off);
      if (v2 > v || (v2 == v && o2 < owner)) { v = v2; owner = o2; }
    }
    float wv = __shfl(v, 0);
    int wo = __shfl(owner, 0);
    if (lane == 0) iouV[unit * KTOP + r] = wv;
    if (lane == wo) {
#pragma unroll
      for (int j = 0; j < KTOP - 1; ++j) iv[j] = iv[j + 1];
      iv[KTOP - 1] = 0.0f;
    }
  }
}

// D3: one WAVE (64-thread block) per g. (a) top-10 of ISPLIT*10 iou values ->
// dynamic_k; (b) cost top-10 over gated candidates — FLATTENED iteration over
// the 8 slices via an LDS cumulative table (full-lane utilization). Gated cost
// is strictly below any ungated/invalid cost when total >= 10; else exact
// full scan. Lexicographic (cost,n) -> order-independent & stable.
__global__ __launch_bounds__(ATPB) void k_merge(
    const float* iouV, const int* gateCnt2, const int* gateList,
    const float* pred, const float* priors, const float* dec, const float* sumL1,
    const u8* validArr, const int* gtl, const float* gtb,
    u32* packed, int G, int N, int C)
{
  int g = blockIdx.x;
  int tid = threadIdx.x;
  int base = g * ISPLIT * KTOP;
  const int TOT = ISPLIT * KTOP;            // 640
  const int PER = TOT / ATPB;               // 10
  __shared__ int scum[GSPLIT + 1];

  if (tid == 0) {
    int t = 0;
    scum[0] = 0;
    for (int s = 0; s < GSPLIT; ++s) { t += gateCnt2[g * GSPLIT + s]; scum[s + 1] = t; }
  }

  // --- dynamic_k from iou top-10 of TOT values (zero-padded; sum invariant) ---
  float il[PER];
#pragma unroll
  for (int k = 0; k < PER; ++k) il[k] = 0.0f;
#pragma unroll
  for (int k = 0; k < PER; ++k) {
    float v = iouV[base + tid + k * ATPB];
    if (v > il[PER - 1]) {
#pragma unroll
      for (int j = 0; j < PER; ++j) {
        if (v > il[j]) { float tv = il[j]; il[j] = v; v = tv; }
      }
    }
  }
  float rv[KTOP];
#pragma unroll
  for (int r = 0; r < KTOP; ++r) {
    float v = il[0]; int owner = tid;
#pragma unroll
    for (int off = 32; off > 0; off >>= 1) {
      float v2 = __shfl_down(v, off);
      int o2 = __shfl_down(owner, off);
      if (v2 > v || (v2 == v && o2 < owner)) { v = v2; owner = o2; }
    }
    float wv = __shfl(v, 0);
    int wo = __shfl(owner, 0);
    rv[r] = wv;
    if (tid == wo) {
#pragma unroll
      for (int j = 0; j < PER - 1; ++j) il[j] = il[j + 1];
      il[PER - 1] = 0.0f;
    }
  }
  // numpy pairwise order for a 10-element sum (all lanes identical)
  float s8 = ((rv[0] + rv[1]) + (rv[2] + rv[3])) + ((rv[4] + rv[5]) + (rv[6] + rv[7]));
  s8 += rv[8];
  s8 += rv[9];
  int dk = (int)s8;  // trunc toward zero == astype(int32)
  if (dk < 1) dk = 1;
  if (dk > KTOP) dk = KTOP;

  float bx0 = gtb[g * 4 + 0], by0 = gtb[g * 4 + 1];
  float bx1 = gtb[g * 4 + 2], by1 = gtb[g * 4 + 3];
  int lab = gtl[g];
  if (lab < 0) lab = 0;
  if (lab >= C) lab = C - 1;

  float cv[KTOP]; int ci[KTOP];
#pragma unroll
  for (int j = 0; j < KTOP; ++j) { cv[j] = 1e30f; ci[j] = INT_MAX; }
  const float4* dec4 = reinterpret_cast<const float4*>(dec);

  __syncthreads();
  int total = scum[GSPLIT];

  if (total >= KTOP) {
    // fast path: gated-only, flattened over slices (gated cost strictly
    // below ungated/invalid when total >= 10)
    for (int i = tid; i < total; i += ATPB) {
      int s = 0;
      while (i >= scum[s + 1]) ++s;   // <= GSPLIT LDS reads
      int idx = i - scum[s];
      int n = gateList[(size_t)(g * GSPLIT + s) * GSLICE + idx];
      float4 d = dec4[n];
      float iou = f_iou(d.x, d.y, d.z, d.w, bx0, by0, bx1, by1);
      float dv = f_dv(pred[(size_t)n * C + lab]);
      float cls = dv - sumL1[n];
      float icost = -logf(iou + 1e-7f);
      float c = (cls * 1.0f + icost * 3.0f) + 0.0f;  // gate true -> +0 exactly
      bool ins = (c < cv[KTOP - 1]) || (c == cv[KTOP - 1] && n < ci[KTOP - 1]);
      if (ins) {
        float cu = c; int cui = n;
#pragma unroll
        for (int j = 0; j < KTOP; ++j) {
          bool lt = (cu < cv[j]) || (cu == cv[j] && cui < ci[j]);
          if (lt) { float tv = cv[j]; int ti = ci[j]; cv[j] = cu; ci[j] = cui; cu = tv; cui = ti; }
        }
      }
    }
  } else {
    // exact full scan (rare: fewer than 10 gated anchors for this g)
    const float4* pri4 = reinterpret_cast<const float4*>(priors);
    for (int n = tid; n < N; n += ATPB) {
      float4 d = dec4[n];
      int vld = validArr[n];
      float iou = f_iou(d.x, d.y, d.z, d.w, bx0, by0, bx1, by1);
      if (!vld) iou = 0.0f;
      float dv = f_dv(pred[(size_t)n * C + lab]);
      float4 pv = pri4[n];
      float c = f_cost(iou, dv, sumL1[n], pv.x, pv.y, pv.z, pv.w,
                       bx0, by0, bx1, by1, vld);
      bool ins = (c < cv[KTOP - 1]) || (c == cv[KTOP - 1] && n < ci[KTOP - 1]);
      if (ins) {
        float cu = c; int cui = n;
#pragma unroll
        for (int j = 0; j < KTOP; ++j) {
          bool lt = (cu < cv[j]) || (cu == cv[j] && cui < ci[j]);
          if (lt) { float tv = cv[j]; int ti = ci[j]; cv[j] = cu; ci[j] = cui; cu = tv; cui = ti; }
        }
      }
    }
  }

  // wave tournament: dk rounds of lexicographic min, scatter
  for (int r = 0; r < KTOP; ++r) {
    float v = cv[0]; int idx = ci[0];
#pragma unroll
    for (int off = 32; off > 0; off >>= 1) {
      float v2 = __shfl_down(v, off);
      int i2 = __shfl_down(idx, off);
      if (v2 < v || (v2 == v && i2 < idx)) { v = v2; idx = i2; }
    }
    int wi = __shfl(idx, 0);
    if (r < dk && tid == 0 && wi >= 0 && wi < N) {
      // count in high 16 bits; sum of g in low 16 (exact g when count==1)
      atomicAdd(&packed[wi], (1u << 16) | (u32)g);
    }
    if (ci[0] == wi && wi != INT_MAX) {  // n unique per g -> one lane pops
#pragma unroll
      for (int j = 0; j < KTOP - 1; ++j) { cv[j] = cv[j + 1]; ci[j] = ci[j + 1]; }
      cv[KTOP - 1] = 1e30f; ci[KTOP - 1] = INT_MAX;
    }
    if (r + 1 >= dk) break;
  }
}

// D4: resolve every anchor. cnt 0/1 inline; cnt>1 handled wave-cooperatively
// (all 64 lanes argmin G gt's for each multi anchor; first-min == np.argmin).
__global__ __launch_bounds__(TPB) void k_phase3(
    const float* pred, const float* priors, const float* dec,
    const float* gtb, const int* gtl, const float* sumL1,
    const u8* validArr, const u32* packed,
    float* out, int N, int G, int C, int Nout)
{
  __shared__ float sg[MAXG * 4];
  __shared__ int sl[MAXG];
  for (int i = threadIdx.x; i < G * 4; i += blockDim.x) sg[i] = gtb[i];
  for (int i = threadIdx.x; i < G; i += blockDim.x) {
    int lb = gtl[i];
    if (lb < 0) lb = 0;
    if (lb >= C) lb = C - 1;
    sl[i] = lb;
  }
  __syncthreads();
  const int tid = threadIdx.x;
  const int lane = tid & 63;
  const float4* dec4 = reinterpret_cast<const float4*>(dec);
  const float4* pri4 = reinterpret_cast<const float4*>(priors);
  int n = blockIdx.x * TPB + tid;
  bool active = (n < N && n < Nout);
  u32 pk = active ? packed[n] : 0;
  int cnt = (int)(pk >> 16);

  if (active && cnt <= 1) {
    float o0 = 0.0f, o1 = -1.0f, o2 = -100000.0f;
    if (cnt == 1) {
      int g = (int)(pk & 0xFFFFu);
      if (g < 0) g = 0;
      if (g >= G) g = G - 1;
      float4 d = dec4[n];
      float x0 = sg[g * 4 + 0], y0 = sg[g * 4 + 1], x1 = sg[g * 4 + 2], y1 = sg[g * 4 + 3];
      float iou = f_iou(d.x, d.y, d.z, d.w, x0, y0, x1, y1);
      if (!validArr[n]) iou = 0.0f;
      o0 = (float)g; o1 = 1.0f; o2 = iou;
    }
    out[n]            = o0;
    out[Nout + n]     = o1;
    out[2 * Nout + n] = o2;
  }

  // wave-cooperative multi-match: argmin over full cost row == np.argmin
  u64 mm = __ballot(active && cnt > 1);
  while (mm) {
    int l = (int)(__ffsll((unsigned long long)mm) - 1);
    mm &= mm - 1;
    int mn = __shfl(n, l);
    float4 dvb = dec4[mn];
    float4 pv = pri4[mn];
    float s1 = sumL1[mn];
    int vld = validArr[mn];
    float best = 1e30f; int bg = INT_MAX;
    for (int gg = lane; gg < G; gg += 64) {
      float x0 = sg[gg * 4 + 0], y0 = sg[gg * 4 + 1];
      float x1 = sg[gg * 4 + 2], y1 = sg[gg * 4 + 3];
      float iou = f_iou(dvb.x, dvb.y, dvb.z, dvb.w, x0, y0, x1, y1);
      if (!vld) iou = 0.0f;
      float dv = f_dv(pred[(size_t)mn * C + sl[gg]]);
      float c = f_cost(iou, dv, s1, pv.x, pv.y, pv.z, pv.w, x0, y0, x1, y1, vld);
      if (c < best || (c == best && gg < bg)) { best = c; bg = gg; }
    }
#pragma unroll
    for (int off = 32; off > 0; off >>= 1) {
      float v2 = __shfl_down(best, off);
      int g2 = __shfl_down(bg, off);
      if (v2 < best || (v2 == best && g2 < bg)) { best = v2; bg = g2; }
    }
    int wg = __shfl(bg, 0);
    if (lane == 0) {
      int g = (wg < 0 || wg >= G) ? 0 : wg;
      float x0 = sg[g * 4 + 0], y0 = sg[g * 4 + 1];
      float x1 = sg[g * 4 + 2], y1 = sg[g * 4 + 3];
      float iou = f_iou(dvb.x, dvb.y, dvb.z, dvb.w, x0, y0, x1, y1);
      if (!vld) iou = 0.0f;
      out[mn]            = (float)g;
      out[Nout + mn]     = 1.0f;
      out[2 * Nout + mn] = iou;
    }
  }
}

extern "C" void kernel_launch(void* const* d_in, const int* in_sizes, int n_in,
                              void* d_out, int out_size, void* d_ws, size_t ws_size,
                              hipStream_t stream) {
  const float* pred   = (const float*)d_in[0];  // (N,C) f32
  const float* priors = (const float*)d_in[1];  // (N,4) f32
  const float* dec    = (const float*)d_in[2];  // (N,4) f32
  const float* gtb    = (const float*)d_in[3];  // (G,4) f32
  const int*   gtl    = (const int*)d_in[4];    // (G,)  int32
  int N = in_sizes[2] / 4;
  int G = in_sizes[3] / 4;
  int C = in_sizes[0] / N;
  int Nout = out_size / 3;
  float* out = (float*)d_out;

  dim3 b(TPB);
  int oblk = (Nout + TPB - 1) / TPB;
  int chunk = (N + GSPLIT - 1) / GSPLIT;
  if (G > MAXG || chunk > GSLICE) {
    k_fb<<<oblk, b, 0, stream>>>(out, Nout, -60000.0f);  // static caps exceeded
    return;
  }

  // ws layout (16B-aligned): packed u32[N] | sumL1 f32[N] | valid u8[N] |
  // gateCnt2 i32[G*GSPLIT] | gateList i32[G*GSPLIT*GSLICE] | iouV f32[G*ISPLIT*10]
  size_t offPacked = 0;
  size_t offSum    = offPacked + (size_t)N * 4;
  size_t offValid  = offSum + (size_t)N * 4;
  size_t offCnt2   = (offValid + (size_t)N + 15) & ~(size_t)15;
  size_t offGlist  = (offCnt2 + (size_t)G * GSPLIT * 4 + 15) & ~(size_t)15;
  size_t offIouV   = offGlist + (size_t)G * GSPLIT * GSLICE * 4;
  size_t need      = offIouV + (size_t)G * ISPLIT * KTOP * 4;
  if (ws_size < need || d_ws == nullptr) {
    k_fb<<<oblk, b, 0, stream>>>(out, Nout, -70000.0f);
    return;
  }
  char* wsb = (char*)d_ws;
  u32* packed   = (u32*)(wsb + offPacked);
  float* sumL1  = (float*)(wsb + offSum);
  u8* validArr  = (u8*)(wsb + offValid);
  int* gateCnt2 = (int*)(wsb + offCnt2);
  int* gateList = (int*)(wsb + offGlist);
  float* iouV   = (float*)(wsb + offIouV);

  int valBlocks = (N * 8 + TPB - 1) / TPB;
  int sumBlocks = (N * 8 + TPB - 1) / TPB;
  int iouBlocks = (G * ISPLIT + 3) / 4;
  int nblk = (N + TPB - 1) / TPB;

  k_prep<<<valBlocks + G * GSPLIT, b, 0, stream>>>(
      priors, gtb, validArr, gateCnt2, gateList, N, G, valBlocks);
  k_sumiou<<<sumBlocks + iouBlocks, b, 0, stream>>>(
      pred, dec, validArr, gtb, sumL1, packed, iouV, N, G, C, sumBlocks);
  k_merge<<<G, dim3(ATPB), 0, stream>>>(
      iouV, gateCnt2, gateList, pred, priors, dec, sumL1, validArr, gtl, gtb,
      packed, G, N, C);
  k_phase3<<<nblk, b, 0, stream>>>(
      pred, priors, dec, gtb, gtl, sumL1, validArr, packed,
      out, N, G, C, Nout);
}